// Round 1
// baseline (1033.244 us; speedup 1.0000x reference)
//
#include <hip/hip_runtime.h>

static constexpr int NN = 50000;   // nodes
static constexpr int NE = 800000;  // edges
static constexpr int NG = 128;     // graphs
static constexpr int H  = 128;     // hidden
static constexpr int NP = 50048;   // padded node count (float slots)

// ---------------- degree histograms ----------------
__global__ void k_deg(const int* __restrict__ src, const int* __restrict__ dst,
                      float* __restrict__ deg_out, float* __restrict__ deg_in) {
  int stride = gridDim.x * blockDim.x;
  for (int e = blockIdx.x * blockDim.x + threadIdx.x; e < NE; e += stride) {
    atomicAdd(&deg_out[src[e]], 1.0f);
    atomicAdd(&deg_in[dst[e]], 1.0f);
  }
}

// ---------------- norms + layer1 pre-message + graph counts ----------------
__global__ void k_norms(const float* __restrict__ deg_out, const float* __restrict__ deg_in,
                        const int* __restrict__ gid,
                        float* __restrict__ norm_out, float* __restrict__ norm_in,
                        float* __restrict__ a1, float* __restrict__ gcnt) {
  int n = blockIdx.x * blockDim.x + threadIdx.x;
  if (n >= NN) return;
  float dov = deg_out[n], din = deg_in[n];
  float no = rsqrtf(fmaxf(dov, 1.0f));
  float ni = rsqrtf(fmaxf(din, 1.0f));
  norm_out[n] = no;
  norm_in[n]  = ni;
  a1[n] = dov * no;                 // h(=out_deg) * norm_out, scalar feature
  atomicAdd(&gcnt[gid[n]], 1.0f);   // graph node counts
}

// ---------------- layer1 scalar scatter: m1[dst] += a1[src] ----------------
__global__ void k_scatter1(const int* __restrict__ src, const int* __restrict__ dst,
                           const float* __restrict__ a1, float* __restrict__ m1) {
  int stride = gridDim.x * blockDim.x;
  for (int e = blockIdx.x * blockDim.x + threadIdx.x; e < NE; e += stride) {
    atomicAdd(&m1[dst[e]], a1[src[e]]);
  }
}

// ---------------- layer1 dense: h2pre[n,j] = relu(m1*ni*W1[j]+b1[j]) * no ----------------
__global__ void k_layer1(const float* __restrict__ m1, const float* __restrict__ norm_in,
                         const float* __restrict__ norm_out,
                         const float* __restrict__ W1, const float* __restrict__ b1,
                         float* __restrict__ h2pre) {
  int t = blockIdx.x * blockDim.x + threadIdx.x;   // thread per (node, 4 features)
  int n = t >> 5;
  if (n >= NN) return;
  int j = (t & 31) * 4;
  float s  = m1[n] * norm_in[n];
  float no = norm_out[n];
  float4 w = *(const float4*)&W1[j];
  float4 b = *(const float4*)&b1[j];
  float4 r;
  r.x = fmaxf(fmaf(s, w.x, b.x), 0.0f) * no;
  r.y = fmaxf(fmaf(s, w.y, b.y), 0.0f) * no;
  r.z = fmaxf(fmaf(s, w.z, b.z), 0.0f) * no;
  r.w = fmaxf(fmaf(s, w.w, b.w), 0.0f) * no;
  *(float4*)&h2pre[(size_t)n * H + j] = r;
}

// ---------------- layer2 vector scatter: m2[dst,:] += h2pre[src,:] ----------------
// one wave per edge; lane l handles features {2l, 2l+1}
__global__ void k_scatter2(const int* __restrict__ src, const int* __restrict__ dst,
                           const float* __restrict__ h2pre, float* __restrict__ m2) {
  int t = blockIdx.x * blockDim.x + threadIdx.x;
  int e = t >> 6;
  if (e >= NE) return;
  int l = t & 63;
  int s = src[e], d = dst[e];
  float2 v = *(const float2*)&h2pre[(size_t)s * H + 2 * l];
  atomicAdd(&m2[(size_t)d * H + 2 * l],     v.x);
  atomicAdd(&m2[(size_t)d * H + 2 * l + 1], v.y);
}

// ---------------- layer2 dense + relu + fused pool@Wc ----------------
// one wave per 4 nodes; lane j holds output features {j, j+64}
__global__ void k_gemm_pool(const float* __restrict__ m2, const float* __restrict__ norm_in,
                            const int* __restrict__ gid,
                            const float* __restrict__ W2, const float* __restrict__ b2,
                            const float* __restrict__ Wc, float* __restrict__ gpart) {
  int t = blockIdx.x * blockDim.x + threadIdx.x;
  int wave = t >> 6, lane = t & 63;
  int n0 = wave * 4;
  if (n0 >= NN) return;

  float2 x0, x1, x2, x3;
  {
    float s0 = norm_in[n0 + 0], s1 = norm_in[n0 + 1];
    float s2 = norm_in[n0 + 2], s3 = norm_in[n0 + 3];
    x0 = *(const float2*)&m2[(size_t)(n0 + 0) * H + 2 * lane]; x0.x *= s0; x0.y *= s0;
    x1 = *(const float2*)&m2[(size_t)(n0 + 1) * H + 2 * lane]; x1.x *= s1; x1.y *= s1;
    x2 = *(const float2*)&m2[(size_t)(n0 + 2) * H + 2 * lane]; x2.x *= s2; x2.y *= s2;
    x3 = *(const float2*)&m2[(size_t)(n0 + 3) * H + 2 * lane]; x3.x *= s3; x3.y *= s3;
  }

  float a00 = 0.f, a01 = 0.f, a10 = 0.f, a11 = 0.f;
  float a20 = 0.f, a21 = 0.f, a30 = 0.f, a31 = 0.f;
#pragma unroll 8
  for (int k = 0; k < 64; ++k) {
    float w0a = W2[(2 * k) * H + lane];
    float w0b = W2[(2 * k) * H + lane + 64];
    float w1a = W2[(2 * k + 1) * H + lane];
    float w1b = W2[(2 * k + 1) * H + lane + 64];
    float xa, xb;
    xa = __shfl(x0.x, k); xb = __shfl(x0.y, k);
    a00 = fmaf(xa, w0a, fmaf(xb, w1a, a00));
    a01 = fmaf(xa, w0b, fmaf(xb, w1b, a01));
    xa = __shfl(x1.x, k); xb = __shfl(x1.y, k);
    a10 = fmaf(xa, w0a, fmaf(xb, w1a, a10));
    a11 = fmaf(xa, w0b, fmaf(xb, w1b, a11));
    xa = __shfl(x2.x, k); xb = __shfl(x2.y, k);
    a20 = fmaf(xa, w0a, fmaf(xb, w1a, a20));
    a21 = fmaf(xa, w0b, fmaf(xb, w1b, a21));
    xa = __shfl(x3.x, k); xb = __shfl(x3.y, k);
    a30 = fmaf(xa, w0a, fmaf(xb, w1a, a30));
    a31 = fmaf(xa, w0b, fmaf(xb, w1b, a31));
  }

  float bb0 = b2[lane], bb1 = b2[lane + 64];
  float4 wc0 = *(const float4*)&Wc[lane * 4];
  float4 wc1 = *(const float4*)&Wc[(lane + 64) * 4];

#pragma unroll
  for (int i = 0; i < 4; ++i) {
    float ai0 = (i == 0) ? a00 : (i == 1) ? a10 : (i == 2) ? a20 : a30;
    float ai1 = (i == 0) ? a01 : (i == 1) ? a11 : (i == 2) ? a21 : a31;
    float h0 = fmaxf(ai0 + bb0, 0.0f);
    float h1 = fmaxf(ai1 + bb1, 0.0f);
    float p0 = fmaf(h0, wc0.x, h1 * wc1.x);
    float p1 = fmaf(h0, wc0.y, h1 * wc1.y);
    float p2 = fmaf(h0, wc0.z, h1 * wc1.z);
    float p3 = fmaf(h0, wc0.w, h1 * wc1.w);
#pragma unroll
    for (int off = 32; off > 0; off >>= 1) {
      p0 += __shfl_xor(p0, off);
      p1 += __shfl_xor(p1, off);
      p2 += __shfl_xor(p2, off);
      p3 += __shfl_xor(p3, off);
    }
    if (lane == 0) {
      int g = gid[n0 + i];
      atomicAdd(&gpart[g * 4 + 0], p0);
      atomicAdd(&gpart[g * 4 + 1], p1);
      atomicAdd(&gpart[g * 4 + 2], p2);
      atomicAdd(&gpart[g * 4 + 3], p3);
    }
  }
}

// ---------------- final: out = gpart/cnt + bc ----------------
__global__ void k_out(const float* __restrict__ gpart, const float* __restrict__ gcnt,
                      const float* __restrict__ bc, float* __restrict__ out) {
  int t = blockIdx.x * blockDim.x + threadIdx.x;
  if (t >= NG * 4) return;
  int g = t >> 2, c = t & 3;
  out[t] = gpart[t] / fmaxf(gcnt[g], 1.0f) + bc[c];
}

extern "C" void kernel_launch(void* const* d_in, const int* in_sizes, int n_in,
                              void* d_out, int out_size, void* d_ws, size_t ws_size,
                              hipStream_t stream) {
  const int*   src = (const int*)d_in[0];
  const int*   dst = (const int*)d_in[1];
  const int*   gid = (const int*)d_in[2];
  const float* W1  = (const float*)d_in[3];
  const float* b1  = (const float*)d_in[4];
  const float* W2  = (const float*)d_in[5];
  const float* b2  = (const float*)d_in[6];
  const float* Wc  = (const float*)d_in[7];
  const float* bc  = (const float*)d_in[8];
  float* out = (float*)d_out;
  float* ws  = (float*)d_ws;

  float* deg_out  = ws;                 // NP
  float* deg_in   = ws + 1 * NP;        // NP
  float* norm_out = ws + 2 * NP;        // NP
  float* norm_in  = ws + 3 * NP;        // NP
  float* a1       = ws + 4 * NP;        // NP
  float* m1       = ws + 5 * NP;        // NP
  float* gpart    = ws + 6 * NP;        // 512
  float* gcnt     = gpart + NG * 4;     // 128
  float* h2pre    = ws + 6 * NP + 1024; // NN*H
  float* m2       = h2pre + (size_t)NN * H; // NN*H

  // zero the accumulators (every call — replays must be correct)
  hipMemsetAsync(deg_out, 0, 2 * NP * sizeof(float), stream);
  hipMemsetAsync(m1, 0, (NP + 1024) * sizeof(float), stream);   // m1 + gpart + gcnt
  hipMemsetAsync(m2, 0, (size_t)NN * H * sizeof(float), stream);

  k_deg<<<1024, 256, 0, stream>>>(src, dst, deg_out, deg_in);
  k_norms<<<(NN + 255) / 256, 256, 0, stream>>>(deg_out, deg_in, gid, norm_out, norm_in, a1, gcnt);
  k_scatter1<<<(NE + 255) / 256, 256, 0, stream>>>(src, dst, a1, m1);
  k_layer1<<<(NN * 32 + 255) / 256, 256, 0, stream>>>(m1, norm_in, norm_out, W1, b1, h2pre);
  k_scatter2<<<(NE * 64) / 256, 256, 0, stream>>>(src, dst, h2pre, m2);
  k_gemm_pool<<<((NN / 4) * 64 + 255) / 256, 256, 0, stream>>>(m2, norm_in, gid, W2, b2, Wc, gpart);
  k_out<<<2, 256, 0, stream>>>(gpart, gcnt, bc, out);
}

// Round 2
// 447.644 us; speedup vs baseline: 2.3082x; 2.3082x over previous
//
#include <hip/hip_runtime.h>

static constexpr int NN = 50000;   // nodes
static constexpr int NE = 800000;  // edges
static constexpr int NG = 128;     // graphs
static constexpr int H  = 128;     // hidden
static constexpr int NP = 50048;   // padded node count
static constexpr int NB = 196;     // scan blocks: 196*256 = 50176 >= NN

// ---------------- degree histograms ----------------
__global__ void k_deg(const int* __restrict__ src, const int* __restrict__ dst,
                      float* __restrict__ deg_out, float* __restrict__ deg_in) {
  int stride = gridDim.x * blockDim.x;
  for (int e = blockIdx.x * blockDim.x + threadIdx.x; e < NE; e += stride) {
    atomicAdd(&deg_out[src[e]], 1.0f);
    atomicAdd(&deg_in[dst[e]], 1.0f);
  }
}

// ---------------- hierarchical exclusive scan of in-degrees ----------------
// A: per-block sums
__global__ void k_scanA(const float* __restrict__ deg_in, int* __restrict__ blocksum) {
  __shared__ int sh[256];
  int t = threadIdx.x;
  int idx = blockIdx.x * 256 + t;
  int v = (idx < NN) ? (int)deg_in[idx] : 0;
  sh[t] = v;
  __syncthreads();
  for (int d = 1; d < 256; d <<= 1) {
    int x = (t >= d) ? sh[t - d] : 0;
    __syncthreads();
    sh[t] += x;
    __syncthreads();
  }
  if (t == 255) blocksum[blockIdx.x] = sh[255];
}
// B: scan the block sums (single block)
__global__ void k_scanB(int* __restrict__ blocksum, int* __restrict__ blockbase) {
  __shared__ int sh[256];
  int t = threadIdx.x;
  int v = (t < NB) ? blocksum[t] : 0;
  sh[t] = v;
  __syncthreads();
  for (int d = 1; d < 256; d <<= 1) {
    int x = (t >= d) ? sh[t - d] : 0;
    __syncthreads();
    sh[t] += x;
    __syncthreads();
  }
  if (t < NB) blockbase[t] = sh[t] - v;   // exclusive
}
// C: final offsets + cursor init
__global__ void k_scanC(const float* __restrict__ deg_in, const int* __restrict__ blockbase,
                        int* __restrict__ off, int* __restrict__ cursor) {
  __shared__ int sh[256];
  int t = threadIdx.x;
  int idx = blockIdx.x * 256 + t;
  int v = (idx < NN) ? (int)deg_in[idx] : 0;
  sh[t] = v;
  __syncthreads();
  for (int d = 1; d < 256; d <<= 1) {
    int x = (t >= d) ? sh[t - d] : 0;
    __syncthreads();
    sh[t] += x;
    __syncthreads();
  }
  if (idx <= NN) {
    int o = blockbase[blockIdx.x] + sh[t] - v;  // exclusive prefix
    off[idx] = o;
    if (idx < NN) cursor[idx] = o;
  }
}

// ---------------- counting-sort fill: esrc grouped by dst ----------------
__global__ void k_fill(const int* __restrict__ src, const int* __restrict__ dst,
                       int* __restrict__ cursor, int* __restrict__ esrc) {
  int stride = gridDim.x * blockDim.x;
  for (int e = blockIdx.x * blockDim.x + threadIdx.x; e < NE; e += stride) {
    int p = atomicAdd(&cursor[dst[e]], 1);
    esrc[p] = src[e];
  }
}

// ---------------- norms + layer1 pre-message + graph counts ----------------
__global__ void k_norms(const float* __restrict__ deg_out, const float* __restrict__ deg_in,
                        const int* __restrict__ gid,
                        float* __restrict__ norm_out, float* __restrict__ norm_in,
                        float* __restrict__ a1, float* __restrict__ gcnt) {
  int n = blockIdx.x * blockDim.x + threadIdx.x;
  if (n >= NN) return;
  float dov = deg_out[n], din = deg_in[n];
  float no = rsqrtf(fmaxf(dov, 1.0f));
  float ni = rsqrtf(fmaxf(din, 1.0f));
  norm_out[n] = no;
  norm_in[n]  = ni;
  a1[n] = dov * no;
  atomicAdd(&gcnt[gid[n]], 1.0f);
}

// ---------------- layer1: CSR gather of a1 + dense(1->128) + relu, fold norm_out ----------------
// one wave per node; lane handles features {2l, 2l+1}
__global__ void k_l1h2(const int* __restrict__ off, const int* __restrict__ esrc,
                       const float* __restrict__ a1,
                       const float* __restrict__ norm_in, const float* __restrict__ norm_out,
                       const float* __restrict__ W1, const float* __restrict__ b1,
                       float* __restrict__ h2pre) {
  int t = blockIdx.x * blockDim.x + threadIdx.x;
  int n = t >> 6, lane = t & 63;
  if (n >= NN) return;
  int o0 = off[n], o1 = off[n + 1];
  float s = 0.0f;
  for (int i = o0 + lane; i < o1; i += 64) s += a1[esrc[i]];
#pragma unroll
  for (int d = 32; d > 0; d >>= 1) s += __shfl_xor(s, d);
  s *= norm_in[n];
  float no = norm_out[n];
  float2 w = *(const float2*)&W1[2 * lane];
  float2 b = *(const float2*)&b1[2 * lane];
  float2 r;
  r.x = fmaxf(fmaf(s, w.x, b.x), 0.0f) * no;
  r.y = fmaxf(fmaf(s, w.y, b.y), 0.0f) * no;
  *(float2*)&h2pre[(size_t)n * H + 2 * lane] = r;
}

// ---------------- layer2: CSR gather + dense + relu + fused pool@Wc ----------------
// one wave per 4 nodes; lane j holds output features {j, j+64}
__global__ void k_gather_gemm_pool(const int* __restrict__ off, const int* __restrict__ esrc,
                                   const float* __restrict__ h2pre,
                                   const float* __restrict__ norm_in, const int* __restrict__ gid,
                                   const float* __restrict__ W2, const float* __restrict__ b2,
                                   const float* __restrict__ Wc, float* __restrict__ gpart) {
  int t = blockIdx.x * blockDim.x + threadIdx.x;
  int wave = t >> 6, lane = t & 63;
  int n0 = wave * 4;
  if (n0 >= NN) return;

  float2 x[4];
#pragma unroll
  for (int i = 0; i < 4; ++i) {
    int n = n0 + i;
    int o0 = off[n], o1 = off[n + 1];
    float2 acc = {0.0f, 0.0f};
    for (int base = o0; base < o1; base += 64) {
      int idx = base + lane;
      int sv = (idx < o1) ? esrc[idx] : 0;
      int cnt = min(64, o1 - base);
      for (int j = 0; j < cnt; ++j) {
        int sn = __shfl(sv, j);
        float2 v = *(const float2*)&h2pre[(size_t)sn * H + 2 * lane];
        acc.x += v.x;
        acc.y += v.y;
      }
    }
    float ni = norm_in[n];
    acc.x *= ni; acc.y *= ni;
    x[i] = acc;
  }

  float a00 = 0.f, a01 = 0.f, a10 = 0.f, a11 = 0.f;
  float a20 = 0.f, a21 = 0.f, a30 = 0.f, a31 = 0.f;
#pragma unroll 8
  for (int k = 0; k < 64; ++k) {
    float w0a = W2[(2 * k) * H + lane];
    float w0b = W2[(2 * k) * H + lane + 64];
    float w1a = W2[(2 * k + 1) * H + lane];
    float w1b = W2[(2 * k + 1) * H + lane + 64];
    float xa, xb;
    xa = __shfl(x[0].x, k); xb = __shfl(x[0].y, k);
    a00 = fmaf(xa, w0a, fmaf(xb, w1a, a00));
    a01 = fmaf(xa, w0b, fmaf(xb, w1b, a01));
    xa = __shfl(x[1].x, k); xb = __shfl(x[1].y, k);
    a10 = fmaf(xa, w0a, fmaf(xb, w1a, a10));
    a11 = fmaf(xa, w0b, fmaf(xb, w1b, a11));
    xa = __shfl(x[2].x, k); xb = __shfl(x[2].y, k);
    a20 = fmaf(xa, w0a, fmaf(xb, w1a, a20));
    a21 = fmaf(xa, w0b, fmaf(xb, w1b, a21));
    xa = __shfl(x[3].x, k); xb = __shfl(x[3].y, k);
    a30 = fmaf(xa, w0a, fmaf(xb, w1a, a30));
    a31 = fmaf(xa, w0b, fmaf(xb, w1b, a31));
  }

  float bb0 = b2[lane], bb1 = b2[lane + 64];
  float4 wc0 = *(const float4*)&Wc[lane * 4];
  float4 wc1 = *(const float4*)&Wc[(lane + 64) * 4];

#pragma unroll
  for (int i = 0; i < 4; ++i) {
    float ai0 = (i == 0) ? a00 : (i == 1) ? a10 : (i == 2) ? a20 : a30;
    float ai1 = (i == 0) ? a01 : (i == 1) ? a11 : (i == 2) ? a21 : a31;
    float h0 = fmaxf(ai0 + bb0, 0.0f);
    float h1 = fmaxf(ai1 + bb1, 0.0f);
    float p0 = fmaf(h0, wc0.x, h1 * wc1.x);
    float p1 = fmaf(h0, wc0.y, h1 * wc1.y);
    float p2 = fmaf(h0, wc0.z, h1 * wc1.z);
    float p3 = fmaf(h0, wc0.w, h1 * wc1.w);
#pragma unroll
    for (int d = 32; d > 0; d >>= 1) {
      p0 += __shfl_xor(p0, d);
      p1 += __shfl_xor(p1, d);
      p2 += __shfl_xor(p2, d);
      p3 += __shfl_xor(p3, d);
    }
    if (lane == 0) {
      int g = gid[n0 + i];
      atomicAdd(&gpart[g * 4 + 0], p0);
      atomicAdd(&gpart[g * 4 + 1], p1);
      atomicAdd(&gpart[g * 4 + 2], p2);
      atomicAdd(&gpart[g * 4 + 3], p3);
    }
  }
}

// ---------------- final: out = gpart/cnt + bc ----------------
__global__ void k_out(const float* __restrict__ gpart, const float* __restrict__ gcnt,
                      const float* __restrict__ bc, float* __restrict__ out) {
  int t = blockIdx.x * blockDim.x + threadIdx.x;
  if (t >= NG * 4) return;
  int g = t >> 2, c = t & 3;
  out[t] = gpart[t] / fmaxf(gcnt[g], 1.0f) + bc[c];
}

extern "C" void kernel_launch(void* const* d_in, const int* in_sizes, int n_in,
                              void* d_out, int out_size, void* d_ws, size_t ws_size,
                              hipStream_t stream) {
  const int*   src = (const int*)d_in[0];
  const int*   dst = (const int*)d_in[1];
  const int*   gid = (const int*)d_in[2];
  const float* W1  = (const float*)d_in[3];
  const float* b1  = (const float*)d_in[4];
  const float* W2  = (const float*)d_in[5];
  const float* b2  = (const float*)d_in[6];
  const float* Wc  = (const float*)d_in[7];
  const float* bc  = (const float*)d_in[8];
  float* out = (float*)d_out;
  float* ws  = (float*)d_ws;

  float* deg_out  = ws;                       // NP
  float* deg_in   = ws + 1 * NP;              // NP
  float* norm_out = ws + 2 * NP;              // NP
  float* norm_in  = ws + 3 * NP;              // NP
  float* a1       = ws + 4 * NP;              // NP
  float* gpart    = ws + 5 * NP;              // 512
  float* gcnt     = gpart + NG * 4;           // 128
  int*   off      = (int*)(ws + 5 * NP + 1024);   // NN+1 (+pad)
  int*   cursor   = off + NP;                 // NN
  int*   blocksum = cursor + NP;              // NB
  int*   blockbase= blocksum + 256;           // NB
  int*   esrc     = blockbase + 256;          // NE
  float* h2pre    = (float*)(esrc + NE);      // NN*H

  // zero accumulators (every call — graph replays must be correct)
  hipMemsetAsync(deg_out, 0, 2 * NP * sizeof(float), stream);
  hipMemsetAsync(gpart, 0, 1024 * sizeof(float), stream);

  k_deg<<<1024, 256, 0, stream>>>(src, dst, deg_out, deg_in);
  k_scanA<<<NB, 256, 0, stream>>>(deg_in, blocksum);
  k_scanB<<<1, 256, 0, stream>>>(blocksum, blockbase);
  k_scanC<<<NB, 256, 0, stream>>>(deg_in, blockbase, off, cursor);
  k_fill<<<1024, 256, 0, stream>>>(src, dst, cursor, esrc);
  k_norms<<<(NN + 255) / 256, 256, 0, stream>>>(deg_out, deg_in, gid, norm_out, norm_in, a1, gcnt);
  k_l1h2<<<(NN * 64) / 256 + 1, 256, 0, stream>>>(off, esrc, a1, norm_in, norm_out, W1, b1, h2pre);
  k_gather_gemm_pool<<<(NN / 4 * 64) / 256, 256, 0, stream>>>(off, esrc, h2pre, norm_in, gid, W2, b2, Wc, gpart);
  k_out<<<2, 256, 0, stream>>>(gpart, gcnt, bc, out);
}

// Round 3
// 404.986 us; speedup vs baseline: 2.5513x; 1.1053x over previous
//
#include <hip/hip_runtime.h>

static constexpr int NN = 50000;   // nodes
static constexpr int NE = 800000;  // edges
static constexpr int NG = 128;     // graphs
static constexpr int H  = 128;     // hidden
static constexpr int NP = 50048;   // padded node count
static constexpr int NB = 196;     // scan blocks: 196*256 = 50176 >= NN

// ---------------- degree histograms ----------------
__global__ void k_deg(const int* __restrict__ src, const int* __restrict__ dst,
                      float* __restrict__ deg_out, float* __restrict__ deg_in) {
  int e = blockIdx.x * blockDim.x + threadIdx.x;
  if (e >= NE) return;
  atomicAdd(&deg_out[src[e]], 1.0f);
  atomicAdd(&deg_in[dst[e]], 1.0f);
}

// ---------------- hierarchical exclusive scan of in-degrees ----------------
__global__ void k_scanA(const float* __restrict__ deg_in, int* __restrict__ blocksum) {
  __shared__ int sh[256];
  int t = threadIdx.x;
  int idx = blockIdx.x * 256 + t;
  int v = (idx < NN) ? (int)deg_in[idx] : 0;
  sh[t] = v;
  __syncthreads();
  for (int d = 1; d < 256; d <<= 1) {
    int x = (t >= d) ? sh[t - d] : 0;
    __syncthreads();
    sh[t] += x;
    __syncthreads();
  }
  if (t == 255) blocksum[blockIdx.x] = sh[255];
}
__global__ void k_scanB(int* __restrict__ blocksum, int* __restrict__ blockbase) {
  __shared__ int sh[256];
  int t = threadIdx.x;
  int v = (t < NB) ? blocksum[t] : 0;
  sh[t] = v;
  __syncthreads();
  for (int d = 1; d < 256; d <<= 1) {
    int x = (t >= d) ? sh[t - d] : 0;
    __syncthreads();
    sh[t] += x;
    __syncthreads();
  }
  if (t < NB) blockbase[t] = sh[t] - v;   // exclusive
}
// scanC + norms + a1 + graph counts fused
__global__ void k_scanC(const float* __restrict__ deg_in, const float* __restrict__ deg_out,
                        const int* __restrict__ blockbase, const int* __restrict__ gid,
                        int* __restrict__ off, int* __restrict__ cursor,
                        float* __restrict__ norm_out, float* __restrict__ norm_in,
                        float* __restrict__ a1, float* __restrict__ gcnt) {
  __shared__ int sh[256];
  int t = threadIdx.x;
  int idx = blockIdx.x * 256 + t;
  int v = (idx < NN) ? (int)deg_in[idx] : 0;
  sh[t] = v;
  __syncthreads();
  for (int d = 1; d < 256; d <<= 1) {
    int x = (t >= d) ? sh[t - d] : 0;
    __syncthreads();
    sh[t] += x;
    __syncthreads();
  }
  if (idx <= NN) {
    int o = blockbase[blockIdx.x] + sh[t] - v;  // exclusive prefix
    off[idx] = o;
    if (idx < NN) cursor[idx] = o;
  }
  if (idx < NN) {
    float dov = deg_out[idx], din = deg_in[idx];
    float no = rsqrtf(fmaxf(dov, 1.0f));
    float ni = rsqrtf(fmaxf(din, 1.0f));
    norm_out[idx] = no;
    norm_in[idx]  = ni;
    a1[idx] = dov * no;
    atomicAdd(&gcnt[gid[idx]], 1.0f);
  }
}

// ---------------- counting-sort fill: esrc grouped by dst ----------------
__global__ void k_fill(const int* __restrict__ src, const int* __restrict__ dst,
                       int* __restrict__ cursor, int* __restrict__ esrc) {
  int e = blockIdx.x * blockDim.x + threadIdx.x;
  if (e >= NE) return;
  int p = atomicAdd(&cursor[dst[e]], 1);
  esrc[p] = src[e];
}

// ---------------- layer1: CSR gather of a1 + dense(1->128) + relu, fold norm_out ----------------
__global__ void k_l1h2(const int* __restrict__ off, const int* __restrict__ esrc,
                       const float* __restrict__ a1,
                       const float* __restrict__ norm_in, const float* __restrict__ norm_out,
                       const float* __restrict__ W1, const float* __restrict__ b1,
                       float* __restrict__ h2pre) {
  int t = blockIdx.x * blockDim.x + threadIdx.x;
  int n = t >> 6, lane = t & 63;
  if (n >= NN) return;
  int o0 = off[n], o1 = off[n + 1];
  float s = 0.0f;
  for (int i = o0 + lane; i < o1; i += 64) s += a1[esrc[i]];
#pragma unroll
  for (int d = 32; d > 0; d >>= 1) s += __shfl_xor(s, d);
  s *= norm_in[n];
  float no = norm_out[n];
  float2 w = *(const float2*)&W1[2 * lane];
  float2 b = *(const float2*)&b1[2 * lane];
  float2 r;
  r.x = fmaxf(fmaf(s, w.x, b.x), 0.0f) * no;
  r.y = fmaxf(fmaf(s, w.y, b.y), 0.0f) * no;
  *(float2*)&h2pre[(size_t)n * H + 2 * lane] = r;
}

// ---------------- layer2 gather: m2[n,:] = ni * sum_{s in N(n)} h2pre[s,:] ----------------
// one wave per node; lane handles features {2l, 2l+1}; 8 independent row loads in flight
__global__ void k_gather(const int* __restrict__ off, const int* __restrict__ esrc,
                         const float* __restrict__ h2pre, const float* __restrict__ norm_in,
                         float* __restrict__ m2) {
  int t = blockIdx.x * blockDim.x + threadIdx.x;
  int n = t >> 6, lane = t & 63;
  if (n >= NN) return;
  int o0 = __builtin_amdgcn_readfirstlane(off[n]);
  int o1 = __builtin_amdgcn_readfirstlane(off[n + 1]);
  float ax = 0.0f, ay = 0.0f;
  int j = o0;
  for (; j + 8 <= o1; j += 8) {
    int i0 = esrc[j + 0], i1 = esrc[j + 1], i2 = esrc[j + 2], i3 = esrc[j + 3];
    int i4 = esrc[j + 4], i5 = esrc[j + 5], i6 = esrc[j + 6], i7 = esrc[j + 7];
    float2 v0 = *(const float2*)&h2pre[(size_t)i0 * H + 2 * lane];
    float2 v1 = *(const float2*)&h2pre[(size_t)i1 * H + 2 * lane];
    float2 v2 = *(const float2*)&h2pre[(size_t)i2 * H + 2 * lane];
    float2 v3 = *(const float2*)&h2pre[(size_t)i3 * H + 2 * lane];
    float2 v4 = *(const float2*)&h2pre[(size_t)i4 * H + 2 * lane];
    float2 v5 = *(const float2*)&h2pre[(size_t)i5 * H + 2 * lane];
    float2 v6 = *(const float2*)&h2pre[(size_t)i6 * H + 2 * lane];
    float2 v7 = *(const float2*)&h2pre[(size_t)i7 * H + 2 * lane];
    ax += v0.x + v1.x + v2.x + v3.x + v4.x + v5.x + v6.x + v7.x;
    ay += v0.y + v1.y + v2.y + v3.y + v4.y + v5.y + v6.y + v7.y;
  }
  if (j < o1) {
    int rem = o1 - j;   // 1..7; esrc padded with zeros past NE, h2pre[0] is valid
    int i0 = esrc[j + 0], i1 = esrc[j + 1], i2 = esrc[j + 2], i3 = esrc[j + 3];
    int i4 = esrc[j + 4], i5 = esrc[j + 5], i6 = esrc[j + 6];
    float2 v0 = *(const float2*)&h2pre[(size_t)i0 * H + 2 * lane];
    float2 v1 = *(const float2*)&h2pre[(size_t)i1 * H + 2 * lane];
    float2 v2 = *(const float2*)&h2pre[(size_t)i2 * H + 2 * lane];
    float2 v3 = *(const float2*)&h2pre[(size_t)i3 * H + 2 * lane];
    float2 v4 = *(const float2*)&h2pre[(size_t)i4 * H + 2 * lane];
    float2 v5 = *(const float2*)&h2pre[(size_t)i5 * H + 2 * lane];
    float2 v6 = *(const float2*)&h2pre[(size_t)i6 * H + 2 * lane];
    ax += v0.x; ay += v0.y;
    if (rem > 1) { ax += v1.x; ay += v1.y; }
    if (rem > 2) { ax += v2.x; ay += v2.y; }
    if (rem > 3) { ax += v3.x; ay += v3.y; }
    if (rem > 4) { ax += v4.x; ay += v4.y; }
    if (rem > 5) { ax += v5.x; ay += v5.y; }
    if (rem > 6) { ax += v6.x; ay += v6.y; }
  }
  float ni = norm_in[n];
  float2 r = {ax * ni, ay * ni};
  *(float2*)&m2[(size_t)n * H + 2 * lane] = r;
}

// ---------------- layer2 dense + relu + fused pool@Wc ----------------
// block = 256 threads = 4 waves; tile = 64 nodes; lane = node, wave = 32-feature strip.
// W2/b2/Wc accesses are wave-uniform -> scalar loads; inner loop is pure v_fmac.
__global__ __launch_bounds__(256) void k_gemm_pool(
    const float* __restrict__ m2, const int* __restrict__ gid,
    const float* __restrict__ W2, const float* __restrict__ b2,
    const float* __restrict__ Wc, float* __restrict__ gpart) {
  int n0 = blockIdx.x * 64;
  int lane = threadIdx.x & 63;
  int w = threadIdx.x >> 6;
  int j0 = __builtin_amdgcn_readfirstlane(w * 32);
  int node = n0 + lane;
  bool valid = node < NN;
  int nrow = valid ? node : NN - 1;
  const float* xrow = m2 + (size_t)nrow * H;

  float acc[32];
#pragma unroll
  for (int f = 0; f < 32; ++f) acc[f] = 0.0f;

  float4 xv = *(const float4*)&xrow[0];
  for (int k4 = 0; k4 < 32; ++k4) {
    float4 nxt = (k4 < 31) ? *(const float4*)&xrow[(k4 + 1) * 4] : xv;
#pragma unroll
    for (int kk = 0; kk < 4; ++kk) {
      int k = k4 * 4 + kk;
      float xk = (kk == 0) ? xv.x : (kk == 1) ? xv.y : (kk == 2) ? xv.z : xv.w;
      const float* wrow = &W2[k * H + j0];
#pragma unroll
      for (int f = 0; f < 32; ++f) acc[f] = fmaf(xk, wrow[f], acc[f]);
    }
    xv = nxt;
  }

  // relu + bias + project onto Wc (4 classes)
  float p0 = 0.f, p1 = 0.f, p2 = 0.f, p3 = 0.f;
#pragma unroll
  for (int f = 0; f < 32; ++f) {
    float h = fmaxf(acc[f] + b2[j0 + f], 0.0f);
    const float* wc = &Wc[(j0 + f) * 4];
    p0 = fmaf(h, wc[0], p0);
    p1 = fmaf(h, wc[1], p1);
    p2 = fmaf(h, wc[2], p2);
    p3 = fmaf(h, wc[3], p3);
  }

  __shared__ float part[4][64][4];
  part[w][lane][0] = p0;
  part[w][lane][1] = p1;
  part[w][lane][2] = p2;
  part[w][lane][3] = p3;
  __syncthreads();
  if (w == 0 && valid) {
    int g = gid[node];
#pragma unroll
    for (int c = 0; c < 4; ++c) {
      float q = part[0][lane][c] + part[1][lane][c] + part[2][lane][c] + part[3][lane][c];
      atomicAdd(&gpart[g * 4 + c], q);
    }
  }
}

// ---------------- final: out = gpart/cnt + bc ----------------
__global__ void k_out(const float* __restrict__ gpart, const float* __restrict__ gcnt,
                      const float* __restrict__ bc, float* __restrict__ out) {
  int t = blockIdx.x * blockDim.x + threadIdx.x;
  if (t >= NG * 4) return;
  int g = t >> 2, c = t & 3;
  out[t] = gpart[t] / fmaxf(gcnt[g], 1.0f) + bc[c];
}

extern "C" void kernel_launch(void* const* d_in, const int* in_sizes, int n_in,
                              void* d_out, int out_size, void* d_ws, size_t ws_size,
                              hipStream_t stream) {
  const int*   src = (const int*)d_in[0];
  const int*   dst = (const int*)d_in[1];
  const int*   gid = (const int*)d_in[2];
  const float* W1  = (const float*)d_in[3];
  const float* b1  = (const float*)d_in[4];
  const float* W2  = (const float*)d_in[5];
  const float* b2  = (const float*)d_in[6];
  const float* Wc  = (const float*)d_in[7];
  const float* bc  = (const float*)d_in[8];
  float* out = (float*)d_out;
  float* ws  = (float*)d_ws;

  float* deg_out  = ws;                       // NP
  float* deg_in   = ws + 1 * NP;              // NP
  float* norm_out = ws + 2 * NP;              // NP
  float* norm_in  = ws + 3 * NP;              // NP
  float* a1       = ws + 4 * NP;              // NP
  float* gpart    = ws + 5 * NP;              // 512
  float* gcnt     = gpart + NG * 4;           // 128
  int*   off      = (int*)(ws + 5 * NP + 1024);   // NP
  int*   cursor   = off + NP;                 // NP
  int*   blocksum = cursor + NP;              // 256
  int*   blockbase= blocksum + 256;           // 256
  int*   esrc     = blockbase + 256;          // NE + 64 pad
  float* h2pre    = (float*)(esrc + NE + 64); // NN*H
  float* m2       = h2pre + (size_t)NN * H;   // NN*H

  // zero accumulators + esrc pad (every call — graph replays must be correct)
  hipMemsetAsync(deg_out, 0, 2 * NP * sizeof(float), stream);
  hipMemsetAsync(gpart, 0, 1024 * sizeof(float), stream);
  hipMemsetAsync(esrc + NE, 0, 64 * sizeof(int), stream);

  k_deg<<<(NE + 255) / 256, 256, 0, stream>>>(src, dst, deg_out, deg_in);
  k_scanA<<<NB, 256, 0, stream>>>(deg_in, blocksum);
  k_scanB<<<1, 256, 0, stream>>>(blocksum, blockbase);
  k_scanC<<<NB, 256, 0, stream>>>(deg_in, deg_out, blockbase, gid, off, cursor,
                                  norm_out, norm_in, a1, gcnt);
  k_fill<<<(NE + 255) / 256, 256, 0, stream>>>(src, dst, cursor, esrc);
  k_l1h2<<<(NN * 64 + 255) / 256, 256, 0, stream>>>(off, esrc, a1, norm_in, norm_out, W1, b1, h2pre);
  k_gather<<<(NN * 64 + 255) / 256, 256, 0, stream>>>(off, esrc, h2pre, norm_in, m2);
  k_gemm_pool<<<(NN + 63) / 64, 256, 0, stream>>>(m2, gid, W2, b2, Wc, gpart);
  k_out<<<2, 256, 0, stream>>>(gpart, gcnt, bc, out);
}

// Round 4
// 391.987 us; speedup vs baseline: 2.6359x; 1.0332x over previous
//
#include <hip/hip_runtime.h>

static constexpr int NN = 50000;   // nodes
static constexpr int NE = 800000;  // edges
static constexpr int NG = 128;     // graphs
static constexpr int H  = 128;     // hidden
static constexpr int NP = 50048;   // padded node count
static constexpr int NB = 196;     // scan blocks: 196*256 = 50176 >= NN

// ---------------- degree histograms ----------------
__global__ void k_deg(const int* __restrict__ src, const int* __restrict__ dst,
                      float* __restrict__ deg_out, float* __restrict__ deg_in) {
  int e = blockIdx.x * blockDim.x + threadIdx.x;
  if (e >= NE) return;
  atomicAdd(&deg_out[src[e]], 1.0f);
  atomicAdd(&deg_in[dst[e]], 1.0f);
}

// ---------------- hierarchical exclusive scan of in-degrees ----------------
__global__ void k_scanA(const float* __restrict__ deg_in, int* __restrict__ blocksum) {
  __shared__ int sh[256];
  int t = threadIdx.x;
  int idx = blockIdx.x * 256 + t;
  int v = (idx < NN) ? (int)deg_in[idx] : 0;
  sh[t] = v;
  __syncthreads();
  for (int d = 1; d < 256; d <<= 1) {
    int x = (t >= d) ? sh[t - d] : 0;
    __syncthreads();
    sh[t] += x;
    __syncthreads();
  }
  if (t == 255) blocksum[blockIdx.x] = sh[255];
}
__global__ void k_scanB(int* __restrict__ blocksum, int* __restrict__ blockbase) {
  __shared__ int sh[256];
  int t = threadIdx.x;
  int v = (t < NB) ? blocksum[t] : 0;
  sh[t] = v;
  __syncthreads();
  for (int d = 1; d < 256; d <<= 1) {
    int x = (t >= d) ? sh[t - d] : 0;
    __syncthreads();
    sh[t] += x;
    __syncthreads();
  }
  if (t < NB) blockbase[t] = sh[t] - v;   // exclusive
}
// scanC + norms + a1 + graph counts fused
__global__ void k_scanC(const float* __restrict__ deg_in, const float* __restrict__ deg_out,
                        const int* __restrict__ blockbase, const int* __restrict__ gid,
                        int* __restrict__ off, int* __restrict__ cursor,
                        float* __restrict__ norm_out, float* __restrict__ norm_in,
                        float* __restrict__ a1, float* __restrict__ gcnt) {
  __shared__ int sh[256];
  int t = threadIdx.x;
  int idx = blockIdx.x * 256 + t;
  int v = (idx < NN) ? (int)deg_in[idx] : 0;
  sh[t] = v;
  __syncthreads();
  for (int d = 1; d < 256; d <<= 1) {
    int x = (t >= d) ? sh[t - d] : 0;
    __syncthreads();
    sh[t] += x;
    __syncthreads();
  }
  if (idx <= NN) {
    int o = blockbase[blockIdx.x] + sh[t] - v;  // exclusive prefix
    off[idx] = o;
    if (idx < NN) cursor[idx] = o;
  }
  if (idx < NN) {
    float dov = deg_out[idx], din = deg_in[idx];
    float no = rsqrtf(fmaxf(dov, 1.0f));
    float ni = rsqrtf(fmaxf(din, 1.0f));
    norm_out[idx] = no;
    norm_in[idx]  = ni;
    a1[idx] = dov * no;
    atomicAdd(&gcnt[gid[idx]], 1.0f);
  }
}

// ---------------- counting-sort fill: esrc grouped by dst ----------------
__global__ void k_fill(const int* __restrict__ src, const int* __restrict__ dst,
                       int* __restrict__ cursor, int* __restrict__ esrc) {
  int e = blockIdx.x * blockDim.x + threadIdx.x;
  if (e >= NE) return;
  int p = atomicAdd(&cursor[dst[e]], 1);
  esrc[p] = src[e];
}

// ---------------- layer1: CSR gather of a1 + dense(1->128) + relu, fold norm_out ----------------
__global__ void k_l1h2(const int* __restrict__ off, const int* __restrict__ esrc,
                       const float* __restrict__ a1,
                       const float* __restrict__ norm_in, const float* __restrict__ norm_out,
                       const float* __restrict__ W1, const float* __restrict__ b1,
                       float* __restrict__ h2pre) {
  int t = blockIdx.x * blockDim.x + threadIdx.x;
  int n = t >> 6, lane = t & 63;
  if (n >= NN) return;
  int o0 = off[n], o1 = off[n + 1];
  float s = 0.0f;
  for (int i = o0 + lane; i < o1; i += 64) s += a1[esrc[i]];
#pragma unroll
  for (int d = 32; d > 0; d >>= 1) s += __shfl_xor(s, d);
  s *= norm_in[n];
  float no = norm_out[n];
  float2 w = *(const float2*)&W1[2 * lane];
  float2 b = *(const float2*)&b1[2 * lane];
  float2 r;
  r.x = fmaxf(fmaf(s, w.x, b.x), 0.0f) * no;
  r.y = fmaxf(fmaf(s, w.y, b.y), 0.0f) * no;
  *(float2*)&h2pre[(size_t)n * H + 2 * lane] = r;
}

// ---------------- fused: layer2 gather (-> LDS) + dense + relu + pool@Wc ----------------
// 64-node tile per block, 256 threads (4 waves).
// Phase 1: wave w gathers nodes [w*16, w*16+16): lane = feature pair {2l,2l+1},
//          writes x-tile to LDS with float4-granular XOR swizzle (c4 ^= row&7).
// Phase 2: wave w computes output strip j in [w*32, w*32+32): lane = node row,
//          ds_read_b128 swizzled (conflict-free), W2/b2/Wc wave-uniform s_loads.
__global__ __launch_bounds__(256) void k_gather_gemm_pool(
    const int* __restrict__ off, const int* __restrict__ esrc,
    const float* __restrict__ h2pre, const float* __restrict__ norm_in,
    const int* __restrict__ gid,
    const float* __restrict__ W2, const float* __restrict__ b2,
    const float* __restrict__ Wc, float* __restrict__ gpart) {
  __shared__ float xt[64 * 128];      // swizzled 64x128 x-tile (32 KB)
  __shared__ float part[4][64][4];    // per-wave class partials (4 KB)

  int n0 = blockIdx.x * 64;
  int lane = threadIdx.x & 63;
  int w = threadIdx.x >> 6;

  // ---- phase 1: gather 16 nodes per wave ----
  for (int i = 0; i < 16; ++i) {
    int row = w * 16 + i;
    int n = n0 + row;
    float ax = 0.0f, ay = 0.0f;
    if (n < NN) {
      int o0 = __builtin_amdgcn_readfirstlane(off[n]);
      int o1 = __builtin_amdgcn_readfirstlane(off[n + 1]);
      int j = o0;
      for (; j + 8 <= o1; j += 8) {
        int i0 = esrc[j + 0], i1 = esrc[j + 1], i2 = esrc[j + 2], i3 = esrc[j + 3];
        int i4 = esrc[j + 4], i5 = esrc[j + 5], i6 = esrc[j + 6], i7 = esrc[j + 7];
        float2 v0 = *(const float2*)&h2pre[(size_t)i0 * H + 2 * lane];
        float2 v1 = *(const float2*)&h2pre[(size_t)i1 * H + 2 * lane];
        float2 v2 = *(const float2*)&h2pre[(size_t)i2 * H + 2 * lane];
        float2 v3 = *(const float2*)&h2pre[(size_t)i3 * H + 2 * lane];
        float2 v4 = *(const float2*)&h2pre[(size_t)i4 * H + 2 * lane];
        float2 v5 = *(const float2*)&h2pre[(size_t)i5 * H + 2 * lane];
        float2 v6 = *(const float2*)&h2pre[(size_t)i6 * H + 2 * lane];
        float2 v7 = *(const float2*)&h2pre[(size_t)i7 * H + 2 * lane];
        ax += v0.x + v1.x + v2.x + v3.x + v4.x + v5.x + v6.x + v7.x;
        ay += v0.y + v1.y + v2.y + v3.y + v4.y + v5.y + v6.y + v7.y;
      }
      if (j < o1) {
        int rem = o1 - j;   // 1..7; esrc padded past NE
        int i0 = esrc[j + 0], i1 = esrc[j + 1], i2 = esrc[j + 2], i3 = esrc[j + 3];
        int i4 = esrc[j + 4], i5 = esrc[j + 5], i6 = esrc[j + 6];
        float2 v0 = *(const float2*)&h2pre[(size_t)i0 * H + 2 * lane];
        float2 v1 = *(const float2*)&h2pre[(size_t)i1 * H + 2 * lane];
        float2 v2 = *(const float2*)&h2pre[(size_t)i2 * H + 2 * lane];
        float2 v3 = *(const float2*)&h2pre[(size_t)i3 * H + 2 * lane];
        float2 v4 = *(const float2*)&h2pre[(size_t)i4 * H + 2 * lane];
        float2 v5 = *(const float2*)&h2pre[(size_t)i5 * H + 2 * lane];
        float2 v6 = *(const float2*)&h2pre[(size_t)i6 * H + 2 * lane];
        ax += v0.x; ay += v0.y;
        if (rem > 1) { ax += v1.x; ay += v1.y; }
        if (rem > 2) { ax += v2.x; ay += v2.y; }
        if (rem > 3) { ax += v3.x; ay += v3.y; }
        if (rem > 4) { ax += v4.x; ay += v4.y; }
        if (rem > 5) { ax += v5.x; ay += v5.y; }
        if (rem > 6) { ax += v6.x; ay += v6.y; }
      }
      float ni = norm_in[n];
      ax *= ni; ay *= ni;
    }
    // swizzled LDS write: features {2l, 2l+1} -> float4 slot (l>>1)^(row&7), half l&1
    int c4 = lane >> 1;
    int word = row * 128 + (((c4 ^ (row & 7)) << 2) | ((lane & 1) << 1));
    float2 r = {ax, ay};
    *(float2*)&xt[word] = r;
  }
  __syncthreads();

  // ---- phase 2: GEMM + relu + Wc projection ----
  int j0 = __builtin_amdgcn_readfirstlane(w * 32);
  int r = lane;                 // node row within tile
  int node = n0 + r;
  bool valid = node < NN;

  float acc[32];
#pragma unroll
  for (int f = 0; f < 32; ++f) acc[f] = 0.0f;

  for (int k4 = 0; k4 < 32; ++k4) {
    float4 x4 = *(const float4*)&xt[r * 128 + ((k4 ^ (r & 7)) << 2)];
#pragma unroll
    for (int kk = 0; kk < 4; ++kk) {
      int k = k4 * 4 + kk;
      float xk = (kk == 0) ? x4.x : (kk == 1) ? x4.y : (kk == 2) ? x4.z : x4.w;
      const float* wrow = &W2[k * H + j0];
#pragma unroll
      for (int f = 0; f < 32; ++f) acc[f] = fmaf(xk, wrow[f], acc[f]);
    }
  }

  float p0 = 0.f, p1 = 0.f, p2 = 0.f, p3 = 0.f;
#pragma unroll
  for (int f = 0; f < 32; ++f) {
    float h = fmaxf(acc[f] + b2[j0 + f], 0.0f);
    const float* wc = &Wc[(j0 + f) * 4];
    p0 = fmaf(h, wc[0], p0);
    p1 = fmaf(h, wc[1], p1);
    p2 = fmaf(h, wc[2], p2);
    p3 = fmaf(h, wc[3], p3);
  }

  part[w][lane][0] = p0;
  part[w][lane][1] = p1;
  part[w][lane][2] = p2;
  part[w][lane][3] = p3;
  __syncthreads();
  if (w == 0 && valid) {
    int g = gid[node];
#pragma unroll
    for (int c = 0; c < 4; ++c) {
      float q = part[0][lane][c] + part[1][lane][c] + part[2][lane][c] + part[3][lane][c];
      atomicAdd(&gpart[g * 4 + c], q);
    }
  }
}

// ---------------- final: out = gpart/cnt + bc ----------------
__global__ void k_out(const float* __restrict__ gpart, const float* __restrict__ gcnt,
                      const float* __restrict__ bc, float* __restrict__ out) {
  int t = blockIdx.x * blockDim.x + threadIdx.x;
  if (t >= NG * 4) return;
  int g = t >> 2, c = t & 3;
  out[t] = gpart[t] / fmaxf(gcnt[g], 1.0f) + bc[c];
}

extern "C" void kernel_launch(void* const* d_in, const int* in_sizes, int n_in,
                              void* d_out, int out_size, void* d_ws, size_t ws_size,
                              hipStream_t stream) {
  const int*   src = (const int*)d_in[0];
  const int*   dst = (const int*)d_in[1];
  const int*   gid = (const int*)d_in[2];
  const float* W1  = (const float*)d_in[3];
  const float* b1  = (const float*)d_in[4];
  const float* W2  = (const float*)d_in[5];
  const float* b2  = (const float*)d_in[6];
  const float* Wc  = (const float*)d_in[7];
  const float* bc  = (const float*)d_in[8];
  float* out = (float*)d_out;
  float* ws  = (float*)d_ws;

  float* deg_out  = ws;                       // NP
  float* deg_in   = ws + 1 * NP;              // NP
  float* norm_out = ws + 2 * NP;              // NP
  float* norm_in  = ws + 3 * NP;              // NP
  float* a1       = ws + 4 * NP;              // NP
  float* gpart    = ws + 5 * NP;              // 512
  float* gcnt     = gpart + NG * 4;           // 128
  int*   off      = (int*)(ws + 5 * NP + 1024);   // NP
  int*   cursor   = off + NP;                 // NP
  int*   blocksum = cursor + NP;              // 256
  int*   blockbase= blocksum + 256;           // 256
  int*   esrc     = blockbase + 256;          // NE + 64 pad
  float* h2pre    = (float*)(esrc + NE + 64); // NN*H

  // zero accumulators + esrc pad (every call — graph replays must be correct)
  hipMemsetAsync(deg_out, 0, 2 * NP * sizeof(float), stream);
  hipMemsetAsync(gpart, 0, 1024 * sizeof(float), stream);
  hipMemsetAsync(esrc + NE, 0, 64 * sizeof(int), stream);

  k_deg<<<(NE + 255) / 256, 256, 0, stream>>>(src, dst, deg_out, deg_in);
  k_scanA<<<NB, 256, 0, stream>>>(deg_in, blocksum);
  k_scanB<<<1, 256, 0, stream>>>(blocksum, blockbase);
  k_scanC<<<NB, 256, 0, stream>>>(deg_in, deg_out, blockbase, gid, off, cursor,
                                  norm_out, norm_in, a1, gcnt);
  k_fill<<<(NE + 255) / 256, 256, 0, stream>>>(src, dst, cursor, esrc);
  k_l1h2<<<(NN * 64 + 255) / 256, 256, 0, stream>>>(off, esrc, a1, norm_in, norm_out, W1, b1, h2pre);
  k_gather_gemm_pool<<<(NN + 63) / 64, 256, 0, stream>>>(off, esrc, h2pre, norm_in, gid,
                                                         W2, b2, Wc, gpart);
  k_out<<<2, 256, 0, stream>>>(gpart, gcnt, bc, out);
}

// Round 5
// 371.169 us; speedup vs baseline: 2.7838x; 1.0561x over previous
//
#include <hip/hip_runtime.h>

static constexpr int NN = 50000;   // nodes
static constexpr int NE = 800000;  // edges
static constexpr int NG = 128;     // graphs
static constexpr int H  = 128;     // hidden
static constexpr int NP = 50048;   // padded node count
static constexpr int NB = 196;     // scan blocks: 196*256 = 50176 >= NN

// ---------------- degree histograms ----------------
__global__ void k_deg(const int* __restrict__ src, const int* __restrict__ dst,
                      float* __restrict__ deg_out, float* __restrict__ deg_in) {
  int e = blockIdx.x * blockDim.x + threadIdx.x;
  if (e >= NE) return;
  atomicAdd(&deg_out[src[e]], 1.0f);
  atomicAdd(&deg_in[dst[e]], 1.0f);
}

// ---------------- hierarchical exclusive scan of in-degrees ----------------
__global__ void k_scanA(const float* __restrict__ deg_in, int* __restrict__ blocksum) {
  __shared__ int sh[256];
  int t = threadIdx.x;
  int idx = blockIdx.x * 256 + t;
  int v = (idx < NN) ? (int)deg_in[idx] : 0;
  sh[t] = v;
  __syncthreads();
  for (int d = 1; d < 256; d <<= 1) {
    int x = (t >= d) ? sh[t - d] : 0;
    __syncthreads();
    sh[t] += x;
    __syncthreads();
  }
  if (t == 255) blocksum[blockIdx.x] = sh[255];
}
__global__ void k_scanB(int* __restrict__ blocksum, int* __restrict__ blockbase) {
  __shared__ int sh[256];
  int t = threadIdx.x;
  int v = (t < NB) ? blocksum[t] : 0;
  sh[t] = v;
  __syncthreads();
  for (int d = 1; d < 256; d <<= 1) {
    int x = (t >= d) ? sh[t - d] : 0;
    __syncthreads();
    sh[t] += x;
    __syncthreads();
  }
  if (t < NB) blockbase[t] = sh[t] - v;   // exclusive
}
// scanC + norms + a1 + graph counts fused
__global__ void k_scanC(const float* __restrict__ deg_in, const float* __restrict__ deg_out,
                        const int* __restrict__ blockbase, const int* __restrict__ gid,
                        int* __restrict__ off, int* __restrict__ cursor,
                        float* __restrict__ norm_out, float* __restrict__ norm_in,
                        float* __restrict__ a1, float* __restrict__ gcnt) {
  __shared__ int sh[256];
  int t = threadIdx.x;
  int idx = blockIdx.x * 256 + t;
  int v = (idx < NN) ? (int)deg_in[idx] : 0;
  sh[t] = v;
  __syncthreads();
  for (int d = 1; d < 256; d <<= 1) {
    int x = (t >= d) ? sh[t - d] : 0;
    __syncthreads();
    sh[t] += x;
    __syncthreads();
  }
  if (idx <= NN) {
    int o = blockbase[blockIdx.x] + sh[t] - v;  // exclusive prefix
    off[idx] = o;
    if (idx < NN) cursor[idx] = o;
  }
  if (idx < NN) {
    float dov = deg_out[idx], din = deg_in[idx];
    float no = rsqrtf(fmaxf(dov, 1.0f));
    float ni = rsqrtf(fmaxf(din, 1.0f));
    norm_out[idx] = no;
    norm_in[idx]  = ni;
    a1[idx] = dov * no;
    atomicAdd(&gcnt[gid[idx]], 1.0f);
  }
}

// ---------------- counting-sort fill: esrc grouped by dst ----------------
__global__ void k_fill(const int* __restrict__ src, const int* __restrict__ dst,
                       int* __restrict__ cursor, int* __restrict__ esrc) {
  int e = blockIdx.x * blockDim.x + threadIdx.x;
  if (e >= NE) return;
  int p = atomicAdd(&cursor[dst[e]], 1);
  esrc[p] = src[e];
}

// ---------------- layer1 reduced to a scalar per node ----------------
// q[n] = ni_n * sum_{s in N(n)} a1[s];  qno[n] = {q, norm_out[n]}
// one wave per node; lane-strided edge loop; butterfly reduce
__global__ void k_q(const int* __restrict__ off, const int* __restrict__ esrc,
                    const float* __restrict__ a1,
                    const float* __restrict__ norm_in, const float* __restrict__ norm_out,
                    float2* __restrict__ qno) {
  int t = blockIdx.x * blockDim.x + threadIdx.x;
  int n = t >> 6, lane = t & 63;
  if (n >= NN) return;
  int o0 = off[n], o1 = off[n + 1];
  float s = 0.0f;
  for (int i = o0 + lane; i < o1; i += 64) s += a1[esrc[i]];
#pragma unroll
  for (int d = 32; d > 0; d >>= 1) s += __shfl_xor(s, d);
  if (lane == 0) {
    float2 r = {s * norm_in[n], norm_out[n]};
    qno[n] = r;
  }
}

// ---------------- fused: layer2 gather (scalar qno, on-the-fly h2) + GEMM + relu + pool@Wc ----
// 64-node tile per block, 512 threads (8 waves).
// Phase 1: wave w gathers rows [w*8, w*8+8). Per neighbor s (wave-uniform scalar load of
//          qno[s]), reconstruct h2pre[s][2l..2l+1] = relu(q*W1+b1)*no in registers.
//          Write x-tile to LDS with float4-granular XOR swizzle (c4 ^= row&7).
// Phase 2: wave w computes 16-feature strip j0=w*16: lane = node row, ds_read_b128
//          swizzled (conflict-free), W2/b2/Wc wave-uniform s_loads, pure v_fmac.
__global__ __launch_bounds__(512) void k_gather_gemm_pool(
    const int* __restrict__ off, const int* __restrict__ esrc,
    const float2* __restrict__ qno, const float* __restrict__ norm_in,
    const int* __restrict__ gid,
    const float* __restrict__ W1, const float* __restrict__ b1,
    const float* __restrict__ W2, const float* __restrict__ b2,
    const float* __restrict__ Wc, float* __restrict__ gpart) {
  __shared__ float xt[64 * 128];      // swizzled 64x128 x-tile (32 KB)
  __shared__ float part[8][64][4];    // per-wave class partials (8 KB)

  int n0 = blockIdx.x * 64;
  int lane = threadIdx.x & 63;
  int w = threadIdx.x >> 6;

  // per-lane layer1 weights for features {2l, 2l+1}
  float2 w1 = *(const float2*)&W1[2 * lane];
  float2 bb = *(const float2*)&b1[2 * lane];

  // ---- phase 1: gather 8 rows per wave ----
  for (int i = 0; i < 8; ++i) {
    int row = w * 8 + i;
    int n = n0 + row;
    float ax = 0.0f, ay = 0.0f;
    if (n < NN) {
      int o0 = __builtin_amdgcn_readfirstlane(off[n]);
      int o1 = __builtin_amdgcn_readfirstlane(off[n + 1]);
      int j = o0;
      for (; j + 8 <= o1; j += 8) {
#pragma unroll
        for (int u = 0; u < 8; ++u) {
          int s = __builtin_amdgcn_readfirstlane(esrc[j + u]);
          float2 v = qno[s];   // wave-uniform -> scalar load
          float hx = fmaxf(fmaf(v.x, w1.x, bb.x), 0.0f);
          float hy = fmaxf(fmaf(v.x, w1.y, bb.y), 0.0f);
          ax = fmaf(hx, v.y, ax);
          ay = fmaf(hy, v.y, ay);
        }
      }
      for (; j < o1; ++j) {
        int s = __builtin_amdgcn_readfirstlane(esrc[j]);
        float2 v = qno[s];
        float hx = fmaxf(fmaf(v.x, w1.x, bb.x), 0.0f);
        float hy = fmaxf(fmaf(v.x, w1.y, bb.y), 0.0f);
        ax = fmaf(hx, v.y, ax);
        ay = fmaf(hy, v.y, ay);
      }
      float ni = norm_in[n];
      ax *= ni; ay *= ni;
    }
    // swizzled LDS write: features {2l,2l+1} -> float4 slot (l>>1)^(row&7), pos 2*(l&1)
    int c4 = lane >> 1;
    int word = row * 128 + (((c4 ^ (row & 7)) << 2) | ((lane & 1) << 1));
    float2 r = {ax, ay};
    *(float2*)&xt[word] = r;
  }
  __syncthreads();

  // ---- phase 2: GEMM + relu + Wc projection ----
  int j0 = __builtin_amdgcn_readfirstlane(w * 16);
  int r = lane;                 // node row within tile
  int node = n0 + r;
  bool valid = node < NN;

  float acc[16];
#pragma unroll
  for (int f = 0; f < 16; ++f) acc[f] = 0.0f;

  for (int k4 = 0; k4 < 32; ++k4) {
    float4 x4 = *(const float4*)&xt[r * 128 + ((k4 ^ (r & 7)) << 2)];
#pragma unroll
    for (int kk = 0; kk < 4; ++kk) {
      int k = k4 * 4 + kk;
      float xk = (kk == 0) ? x4.x : (kk == 1) ? x4.y : (kk == 2) ? x4.z : x4.w;
      const float* wrow = &W2[k * H + j0];
#pragma unroll
      for (int f = 0; f < 16; ++f) acc[f] = fmaf(xk, wrow[f], acc[f]);
    }
  }

  float p0 = 0.f, p1 = 0.f, p2 = 0.f, p3 = 0.f;
#pragma unroll
  for (int f = 0; f < 16; ++f) {
    float h = fmaxf(acc[f] + b2[j0 + f], 0.0f);
    const float* wc = &Wc[(j0 + f) * 4];
    p0 = fmaf(h, wc[0], p0);
    p1 = fmaf(h, wc[1], p1);
    p2 = fmaf(h, wc[2], p2);
    p3 = fmaf(h, wc[3], p3);
  }

  part[w][lane][0] = p0;
  part[w][lane][1] = p1;
  part[w][lane][2] = p2;
  part[w][lane][3] = p3;
  __syncthreads();
  if (w == 0 && valid) {
    int g = gid[node];
    float q0 = 0.f, q1 = 0.f, q2 = 0.f, q3 = 0.f;
#pragma unroll
    for (int ww = 0; ww < 8; ++ww) {
      q0 += part[ww][lane][0];
      q1 += part[ww][lane][1];
      q2 += part[ww][lane][2];
      q3 += part[ww][lane][3];
    }
    atomicAdd(&gpart[g * 4 + 0], q0);
    atomicAdd(&gpart[g * 4 + 1], q1);
    atomicAdd(&gpart[g * 4 + 2], q2);
    atomicAdd(&gpart[g * 4 + 3], q3);
  }
}

// ---------------- final: out = gpart/cnt + bc ----------------
__global__ void k_out(const float* __restrict__ gpart, const float* __restrict__ gcnt,
                      const float* __restrict__ bc, float* __restrict__ out) {
  int t = blockIdx.x * blockDim.x + threadIdx.x;
  if (t >= NG * 4) return;
  int g = t >> 2, c = t & 3;
  out[t] = gpart[t] / fmaxf(gcnt[g], 1.0f) + bc[c];
}

extern "C" void kernel_launch(void* const* d_in, const int* in_sizes, int n_in,
                              void* d_out, int out_size, void* d_ws, size_t ws_size,
                              hipStream_t stream) {
  const int*   src = (const int*)d_in[0];
  const int*   dst = (const int*)d_in[1];
  const int*   gid = (const int*)d_in[2];
  const float* W1  = (const float*)d_in[3];
  const float* b1  = (const float*)d_in[4];
  const float* W2  = (const float*)d_in[5];
  const float* b2  = (const float*)d_in[6];
  const float* Wc  = (const float*)d_in[7];
  const float* bc  = (const float*)d_in[8];
  float* out = (float*)d_out;
  float* ws  = (float*)d_ws;

  float* deg_out  = ws;                       // NP
  float* deg_in   = ws + 1 * NP;              // NP
  float* norm_out = ws + 2 * NP;              // NP
  float* norm_in  = ws + 3 * NP;              // NP
  float* a1       = ws + 4 * NP;              // NP
  float* gpart    = ws + 5 * NP;              // 512
  float* gcnt     = gpart + NG * 4;           // 128
  int*   off      = (int*)(ws + 5 * NP + 1024);   // NP
  int*   cursor   = off + NP;                 // NP
  int*   blocksum = cursor + NP;              // 256
  int*   blockbase= blocksum + 256;           // 256
  int*   esrc     = blockbase + 256;          // NE + 64 pad
  float2* qno     = (float2*)(esrc + NE + 64); // NP float2

  // zero accumulators + esrc pad (every call — graph replays must be correct)
  hipMemsetAsync(deg_out, 0, 2 * NP * sizeof(float), stream);
  hipMemsetAsync(gpart, 0, 1024 * sizeof(float), stream);
  hipMemsetAsync(esrc + NE, 0, 64 * sizeof(int), stream);

  k_deg<<<(NE + 255) / 256, 256, 0, stream>>>(src, dst, deg_out, deg_in);
  k_scanA<<<NB, 256, 0, stream>>>(deg_in, blocksum);
  k_scanB<<<1, 256, 0, stream>>>(blocksum, blockbase);
  k_scanC<<<NB, 256, 0, stream>>>(deg_in, deg_out, blockbase, gid, off, cursor,
                                  norm_out, norm_in, a1, gcnt);
  k_fill<<<(NE + 255) / 256, 256, 0, stream>>>(src, dst, cursor, esrc);
  k_q<<<(NN * 64 + 255) / 256, 256, 0, stream>>>(off, esrc, a1, norm_in, norm_out, qno);
  k_gather_gemm_pool<<<(NN + 63) / 64, 512, 0, stream>>>(off, esrc, qno, norm_in, gid,
                                                         W1, b1, W2, b2, Wc, gpart);
  k_out<<<2, 256, 0, stream>>>(gpart, gcnt, bc, out);
}

// Round 6
// 348.455 us; speedup vs baseline: 2.9652x; 1.0652x over previous
//
#include <hip/hip_runtime.h>

static constexpr int NN = 50000;   // nodes
static constexpr int NE = 800000;  // edges
static constexpr int NG = 128;     // graphs
static constexpr int H  = 128;     // hidden
static constexpr int NP = 50048;   // padded node count
static constexpr int NB = 196;     // scan blocks: 196*256 = 50176 >= NN

// ---------------- degree histograms ----------------
__global__ void k_deg(const int* __restrict__ src, const int* __restrict__ dst,
                      float* __restrict__ deg_out, float* __restrict__ deg_in) {
  int e = blockIdx.x * blockDim.x + threadIdx.x;
  if (e >= NE) return;
  atomicAdd(&deg_out[src[e]], 1.0f);
  atomicAdd(&deg_in[dst[e]], 1.0f);
}

// ---------------- hierarchical exclusive scan of in-degrees ----------------
__global__ void k_scanA(const float* __restrict__ deg_in, int* __restrict__ blocksum) {
  __shared__ int sh[256];
  int t = threadIdx.x;
  int idx = blockIdx.x * 256 + t;
  int v = (idx < NN) ? (int)deg_in[idx] : 0;
  sh[t] = v;
  __syncthreads();
  for (int d = 1; d < 256; d <<= 1) {
    int x = (t >= d) ? sh[t - d] : 0;
    __syncthreads();
    sh[t] += x;
    __syncthreads();
  }
  if (t == 255) blocksum[blockIdx.x] = sh[255];
}
__global__ void k_scanB(int* __restrict__ blocksum, int* __restrict__ blockbase) {
  __shared__ int sh[256];
  int t = threadIdx.x;
  int v = (t < NB) ? blocksum[t] : 0;
  sh[t] = v;
  __syncthreads();
  for (int d = 1; d < 256; d <<= 1) {
    int x = (t >= d) ? sh[t - d] : 0;
    __syncthreads();
    sh[t] += x;
    __syncthreads();
  }
  if (t < NB) blockbase[t] = sh[t] - v;   // exclusive
}
// scanC + norms + a1 + graph counts fused
__global__ void k_scanC(const float* __restrict__ deg_in, const float* __restrict__ deg_out,
                        const int* __restrict__ blockbase, const int* __restrict__ gid,
                        int* __restrict__ off, int* __restrict__ cursor,
                        float* __restrict__ norm_out, float* __restrict__ norm_in,
                        float* __restrict__ a1, float* __restrict__ gcnt) {
  __shared__ int sh[256];
  int t = threadIdx.x;
  int idx = blockIdx.x * 256 + t;
  int v = (idx < NN) ? (int)deg_in[idx] : 0;
  sh[t] = v;
  __syncthreads();
  for (int d = 1; d < 256; d <<= 1) {
    int x = (t >= d) ? sh[t - d] : 0;
    __syncthreads();
    sh[t] += x;
    __syncthreads();
  }
  if (idx <= NN) {
    int o = blockbase[blockIdx.x] + sh[t] - v;  // exclusive prefix
    off[idx] = o;
    if (idx < NN) cursor[idx] = o;
  }
  if (idx < NN) {
    float dov = deg_out[idx], din = deg_in[idx];
    float no = rsqrtf(fmaxf(dov, 1.0f));
    float ni = rsqrtf(fmaxf(din, 1.0f));
    norm_out[idx] = no;
    norm_in[idx]  = ni;
    a1[idx] = dov * no;
    atomicAdd(&gcnt[gid[idx]], 1.0f);
  }
}

// ---------------- counting-sort fill: esrc grouped by dst ----------------
__global__ void k_fill(const int* __restrict__ src, const int* __restrict__ dst,
                       int* __restrict__ cursor, int* __restrict__ esrc) {
  int e = blockIdx.x * blockDim.x + threadIdx.x;
  if (e >= NE) return;
  int p = atomicAdd(&cursor[dst[e]], 1);
  esrc[p] = src[e];
}

// ---------------- layer1 reduced to a scalar per node ----------------
// q[n] = ni_n * sum_{s in N(n)} a1[s];  qno[n] = {q, norm_out[n]}
// 16-lane group per node (4 nodes/wave)
__global__ void k_q(const int* __restrict__ off, const int* __restrict__ esrc,
                    const float* __restrict__ a1,
                    const float* __restrict__ norm_in, const float* __restrict__ norm_out,
                    float2* __restrict__ qno) {
  int t = blockIdx.x * blockDim.x + threadIdx.x;
  int n = t >> 4, sub = t & 15;
  if (n >= NN) return;
  int o0 = off[n], o1 = off[n + 1];
  float s = 0.0f;
  for (int i = o0 + sub; i < o1; i += 16) s += a1[esrc[i]];
#pragma unroll
  for (int d = 8; d > 0; d >>= 1) s += __shfl_xor(s, d);   // reduce within 16-group
  if (sub == 0) {
    float2 r;
    r.x = s * norm_in[n];
    r.y = norm_out[n];
    qno[n] = r;
  }
}

// ---------------- fused: layer2 gather (lane-parallel qno + shfl broadcast) + GEMM + pool ----
// 64-node tile per block, 512 threads (8 waves).
// Phase 1: wave w builds rows [w*8, w*8+8). Per row: one vector load of <=64 esrc,
//          one vector gather of <=64 qno (MLP 64), then per-neighbor __shfl broadcast
//          reconstructs h2[s][2l..2l+1] = relu(q*W1+b1)*no in registers.
//          Write x-tile to LDS with float4-granular XOR swizzle (c4 ^= row&7).
// Phase 2: wave w computes 16-feature strip j0=w*16: lane = node row, ds_read_b128
//          swizzled (conflict-free), W2/b2/Wc wave-uniform s_loads, pure v_fmac.
__global__ __launch_bounds__(512) void k_gather_gemm_pool(
    const int* __restrict__ off, const int* __restrict__ esrc,
    const float2* __restrict__ qno, const float* __restrict__ norm_in,
    const int* __restrict__ gid,
    const float* __restrict__ W1, const float* __restrict__ b1,
    const float* __restrict__ W2, const float* __restrict__ b2,
    const float* __restrict__ Wc, float* __restrict__ gpart) {
  __shared__ float xt[64 * 128];      // swizzled 64x128 x-tile (32 KB)
  __shared__ float part[8][64][4];    // per-wave class partials (8 KB)

  int n0 = blockIdx.x * 64;
  int lane = threadIdx.x & 63;
  int w = threadIdx.x >> 6;

  // per-lane layer1 weights for features {2l, 2l+1}
  float2 w1 = *(const float2*)&W1[2 * lane];
  float2 bb = *(const float2*)&b1[2 * lane];

  // ---- phase 1: build 8 rows per wave ----
  for (int i = 0; i < 8; ++i) {
    int row = w * 8 + i;
    int n = n0 + row;
    float ax = 0.0f, ay = 0.0f;
    if (n < NN) {
      int o0 = __builtin_amdgcn_readfirstlane(off[n]);
      int o1 = __builtin_amdgcn_readfirstlane(off[n + 1]);
      for (int base = o0; base < o1; base += 64) {
        int idx = base + lane;
        int s = (idx < o1) ? esrc[idx] : 0;   // vector load (coalesced)
        float2 v = qno[s];                    // vector gather, 64 lanes in flight
        int cnt = min(64, o1 - base);
        int u = 0;
        for (; u + 4 <= cnt; u += 4) {
#pragma unroll
          for (int uu = 0; uu < 4; ++uu) {
            float qv  = __shfl(v.x, u + uu);
            float nov = __shfl(v.y, u + uu);
            float hx = fmaxf(fmaf(qv, w1.x, bb.x), 0.0f);
            float hy = fmaxf(fmaf(qv, w1.y, bb.y), 0.0f);
            ax = fmaf(hx, nov, ax);
            ay = fmaf(hy, nov, ay);
          }
        }
        for (; u < cnt; ++u) {
          float qv  = __shfl(v.x, u);
          float nov = __shfl(v.y, u);
          float hx = fmaxf(fmaf(qv, w1.x, bb.x), 0.0f);
          float hy = fmaxf(fmaf(qv, w1.y, bb.y), 0.0f);
          ax = fmaf(hx, nov, ax);
          ay = fmaf(hy, nov, ay);
        }
      }
      float ni = norm_in[n];
      ax *= ni; ay *= ni;
    }
    // swizzled LDS write: features {2l,2l+1} -> float4 slot (l>>1)^(row&7), pos 2*(l&1)
    int c4 = lane >> 1;
    int word = row * 128 + (((c4 ^ (row & 7)) << 2) | ((lane & 1) << 1));
    float2 r = {ax, ay};
    *(float2*)&xt[word] = r;
  }
  __syncthreads();

  // ---- phase 2: GEMM + relu + Wc projection ----
  int j0 = __builtin_amdgcn_readfirstlane(w * 16);
  int r = lane;                 // node row within tile
  int node = n0 + r;
  bool valid = node < NN;

  float acc[16];
#pragma unroll
  for (int f = 0; f < 16; ++f) acc[f] = 0.0f;

  for (int k4 = 0; k4 < 32; ++k4) {
    float4 x4 = *(const float4*)&xt[r * 128 + ((k4 ^ (r & 7)) << 2)];
#pragma unroll
    for (int kk = 0; kk < 4; ++kk) {
      int k = k4 * 4 + kk;
      float xk = (kk == 0) ? x4.x : (kk == 1) ? x4.y : (kk == 2) ? x4.z : x4.w;
      const float* wrow = &W2[k * H + j0];
#pragma unroll
      for (int f = 0; f < 16; ++f) acc[f] = fmaf(xk, wrow[f], acc[f]);
    }
  }

  float p0 = 0.f, p1 = 0.f, p2 = 0.f, p3 = 0.f;
#pragma unroll
  for (int f = 0; f < 16; ++f) {
    float h = fmaxf(acc[f] + b2[j0 + f], 0.0f);
    const float* wc = &Wc[(j0 + f) * 4];
    p0 = fmaf(h, wc[0], p0);
    p1 = fmaf(h, wc[1], p1);
    p2 = fmaf(h, wc[2], p2);
    p3 = fmaf(h, wc[3], p3);
  }

  part[w][lane][0] = p0;
  part[w][lane][1] = p1;
  part[w][lane][2] = p2;
  part[w][lane][3] = p3;
  __syncthreads();
  if (w == 0 && valid) {
    int g = gid[node];
    float q0 = 0.f, q1 = 0.f, q2 = 0.f, q3 = 0.f;
#pragma unroll
    for (int ww = 0; ww < 8; ++ww) {
      q0 += part[ww][lane][0];
      q1 += part[ww][lane][1];
      q2 += part[ww][lane][2];
      q3 += part[ww][lane][3];
    }
    atomicAdd(&gpart[g * 4 + 0], q0);
    atomicAdd(&gpart[g * 4 + 1], q1);
    atomicAdd(&gpart[g * 4 + 2], q2);
    atomicAdd(&gpart[g * 4 + 3], q3);
  }
}

// ---------------- final: out = gpart/cnt + bc ----------------
__global__ void k_out(const float* __restrict__ gpart, const float* __restrict__ gcnt,
                      const float* __restrict__ bc, float* __restrict__ out) {
  int t = blockIdx.x * blockDim.x + threadIdx.x;
  if (t >= NG * 4) return;
  int g = t >> 2, c = t & 3;
  out[t] = gpart[t] / fmaxf(gcnt[g], 1.0f) + bc[c];
}

extern "C" void kernel_launch(void* const* d_in, const int* in_sizes, int n_in,
                              void* d_out, int out_size, void* d_ws, size_t ws_size,
                              hipStream_t stream) {
  const int*   src = (const int*)d_in[0];
  const int*   dst = (const int*)d_in[1];
  const int*   gid = (const int*)d_in[2];
  const float* W1  = (const float*)d_in[3];
  const float* b1  = (const float*)d_in[4];
  const float* W2  = (const float*)d_in[5];
  const float* b2  = (const float*)d_in[6];
  const float* Wc  = (const float*)d_in[7];
  const float* bc  = (const float*)d_in[8];
  float* out = (float*)d_out;
  float* ws  = (float*)d_ws;

  // zeroed region first (one memset): deg_out | deg_in | gpart | gcnt (+pad)
  float* deg_out  = ws;                       // NP
  float* deg_in   = ws + NP;                  // NP
  float* gpart    = ws + 2 * NP;              // 512
  float* gcnt     = ws + 2 * NP + 512;        // 128 (+384 pad)
  float* norm_out = ws + 2 * NP + 1024;       // NP
  float* norm_in  = norm_out + NP;            // NP
  float* a1       = norm_in + NP;             // NP
  int*   off      = (int*)(a1 + NP);          // NP
  int*   cursor   = off + NP;                 // NP
  int*   blocksum = cursor + NP;              // 256
  int*   blockbase= blocksum + 256;           // 256
  int*   esrc     = blockbase + 256;          // NE
  float2* qno     = (float2*)(esrc + NE);     // NP float2 (8B-aligned: offset even)

  // zero accumulators (every call — graph replays must be correct)
  hipMemsetAsync(deg_out, 0, (2 * NP + 1024) * sizeof(float), stream);

  k_deg<<<(NE + 255) / 256, 256, 0, stream>>>(src, dst, deg_out, deg_in);
  k_scanA<<<NB, 256, 0, stream>>>(deg_in, blocksum);
  k_scanB<<<1, 256, 0, stream>>>(blocksum, blockbase);
  k_scanC<<<NB, 256, 0, stream>>>(deg_in, deg_out, blockbase, gid, off, cursor,
                                  norm_out, norm_in, a1, gcnt);
  k_fill<<<(NE + 255) / 256, 256, 0, stream>>>(src, dst, cursor, esrc);
  k_q<<<(NN * 16 + 255) / 256, 256, 0, stream>>>(off, esrc, a1, norm_in, norm_out, qno);
  k_gather_gemm_pool<<<(NN + 63) / 64, 512, 0, stream>>>(off, esrc, qno, norm_in, gid,
                                                         W1, b1, W2, b2, Wc, gpart);
  k_out<<<2, 256, 0, stream>>>(gpart, gcnt, bc, out);
}